// Round 2
// 225.885 us; speedup vs baseline: 1.5583x; 1.5583x over previous
//
#include <hip/hip_runtime.h>
#include <math.h>

// Problem constants (match reference)
#define B_   16
#define T_   1024
#define F_   512
#define G_   2
#define V_   320
#define D_   128
#define N_   (B_ * T_)      // 16384 tokens
#define GV   (G_ * V_)      // 640
#define EPS_ 1e-7f

// Fused-GEMM config: 3-pass f16 limb-split MFMA
//   logits = xh*wh + 2^-11*(xh*wl' + xl'*wh),  xl' = f16((x - f16(x))*2048)
#define ROWS    64
#define THREADS 512          // 8 waves: 2(M) x 4(N) wave grid, wave tile 32x160
#define NBLK    (N_ / ROWS)  // 256 blocks -> 1 block/CU, grid fully resident
#define CHK     32           // k elems (f16) staged per chunk
#define NCH     (F_ / CHK)   // 16 chunks per pass
#define NCC     (3 * NCH)    // 48 chunks total: lh, hl, hh passes

// LDS: B tile 640 x 32 f16 (40960 B, 64 B/row) + A tile 64 x 32 f16 (4096 B)
#define BOFF 0
#define AOFF 40960
#define LDSZ 45056

typedef _Float16 half8 __attribute__((ext_vector_type(8)));
typedef _Float16 half4 __attribute__((ext_vector_type(4)));
typedef float f32x16 __attribute__((ext_vector_type(16)));

// Workspace layout (float slots). counts is PACKED u32 (2 x 16-bit fields per
// word, count<=B_=16 so no carry) -> total 821248 floats = 3.28 MB, strictly
// under the 3.94 MB footprint proven safe in the prior session.
#define CNTW      (T_ * G_ * (V_ / 2))      // 327680 u32 words
#define WS_COUNTS 0
#define WS_AVG    CNTW                      // NBLK*GV = 163840
#define WS_ENT    (WS_AVG + NBLK * GV)      // T_*G_   = 2048
#define WS_WH     (WS_ENT + T_ * G_)        // GV*F_ f16 = 163840 float slots
#define WS_WL     (WS_WH + (GV * F_ / 2))   // GV*F_ f16 = 163840 float slots

// ---- w -> (wh, wl') f16 limbs, [GV][F_] row-major ----
__global__ __launch_bounds__(512) void k_conv_w(
    const float* __restrict__ w, _Float16* __restrict__ wh, _Float16* __restrict__ wl)
{
  const int i = blockIdx.x * 512 + threadIdx.x;  // 81920 float4s
  const float4 v = ((const float4*)w)[i];
  half4 h, l;
#pragma unroll
  for (int k = 0; k < 4; ++k) {
    const float vk = ((const float*)&v)[k];
    const _Float16 hk = (_Float16)vk;
    h[k] = hk;
    l[k] = (_Float16)((vk - (float)hk) * 2048.0f);
  }
  ((half4*)wh)[i] = h;
  ((half4*)wl)[i] = l;
}

// Fused: 3-pass limb-split MFMA GEMM + softmax stats + argmaxes + gather.
__global__ __launch_bounds__(THREADS, 2) void k_fused(
    const float* __restrict__ x, const _Float16* __restrict__ wh,
    const _Float16* __restrict__ wl, const float* __restrict__ bias,
    const float* __restrict__ cb, const float* __restrict__ gum,
    float* __restrict__ out, unsigned* __restrict__ counts,
    float* __restrict__ avg_part)
{
  __shared__ __align__(16) unsigned char SB[LDSZ];
  const int tid = threadIdx.x;
  const int wv  = tid >> 6;           // 0..7
  const int ln  = tid & 63;
  const int lo  = ln & 31, hi = ln >> 5;
  const int wvm = wv >> 2, wvn = wv & 3;
  const int blk = blockIdx.x;
  const int n0  = blk * ROWS;

  f32x16 acc[5];
#pragma unroll
  for (int t = 0; t < 5; ++t)
#pragma unroll
    for (int i = 0; i < 16; ++i) acc[t][i] = 0.0f;

  // staging slot assignment
  const int arow = tid >> 3, asub = tid & 7;   // A: 64 rows x 8 float4-slots
  const int aq = asub >> 1, ah = asub & 1;
  const float4* x4f = (const float4*)x;

  // hoisted fragment read addresses (loop-invariant; swizzle q ^= row&3)
  int aaddr[2], baddr[5][2];
  {
    const int ar = wvm * 32 + lo;
#pragma unroll
    for (int ks = 0; ks < 2; ++ks)
      aaddr[ks] = AOFF + ar * 64 + (((2 * ks + hi) ^ (ar & 3)) << 4);
#pragma unroll
    for (int t = 0; t < 5; ++t) {
      const int bn = wvn * 160 + t * 32 + lo;
#pragma unroll
      for (int ks = 0; ks < 2; ++ks)
        baddr[t][ks] = BOFF + bn * 64 + (((2 * ks + hi) ^ (bn & 3)) << 4);
    }
  }

  half8 bpre[5];
  float4 xpre;

  // ---- prologue: load + stage chunk 0 (phase 0: A=xl', B=wh) ----
#pragma unroll
  for (int it = 0; it < 5; ++it) {
    const int s = tid + it * THREADS;
    const int n = s >> 2, q = s & 3;
    bpre[it] = ((const half8*)wh)[n * 64 + q];
  }
  xpre = x4f[(size_t)(n0 + arow) * (F_ / 4) + asub];
  {
#pragma unroll
    for (int it = 0; it < 5; ++it) {
      const int s = tid + it * THREADS;
      const int n = s >> 2, q = s & 3;
      *(half8*)(SB + BOFF + n * 64 + ((q ^ (n & 3)) << 4)) = bpre[it];
    }
    half4 a4;
#pragma unroll
    for (int k = 0; k < 4; ++k) {
      const float vk = ((const float*)&xpre)[k];
      const _Float16 hk = (_Float16)vk;
      a4[k] = (_Float16)((vk - (float)hk) * 2048.0f);   // low limb for pass 0
    }
    *(half4*)(SB + AOFF + arow * 64 + ((aq ^ (arow & 3)) << 4) + ah * 8) = a4;
  }
  __syncthreads();

  // ---- main loop: 48 chunks (16 lh, 16 hl, 16 hh) ----
  for (int cc = 0; cc < NCC; ++cc) {
    const int cc1 = cc + 1;
    if (cc1 < NCC) {  // prefetch next chunk into registers
      const int ph1 = cc1 >> 4;
      const _Float16* bs = (ph1 == 1) ? wl : wh;
      const int k08 = (cc1 & 15) * 4;
#pragma unroll
      for (int it = 0; it < 5; ++it) {
        const int s = tid + it * THREADS;
        const int n = s >> 2, q = s & 3;
        bpre[it] = ((const half8*)bs)[n * 64 + k08 + q];
      }
      xpre = x4f[(size_t)(n0 + arow) * (F_ / 4) + (cc1 & 15) * 8 + asub];
    }
    // compute current chunk from LDS
#pragma unroll
    for (int ks = 0; ks < 2; ++ks) {
      const half8 af = *(const half8*)(SB + aaddr[ks]);
#pragma unroll
      for (int t = 0; t < 5; ++t) {
        const half8 bf = *(const half8*)(SB + baddr[t][ks]);
        acc[t] = __builtin_amdgcn_mfma_f32_32x32x16_f16(af, bf, acc[t], 0, 0, 0);
      }
    }
    if (cc == 2 * NCH - 1) {  // finished lh+hl: scale the low-limb partial
#pragma unroll
      for (int t = 0; t < 5; ++t)
#pragma unroll
        for (int i = 0; i < 16; ++i) acc[t][i] *= (1.0f / 2048.0f);
    }
    __syncthreads();
    if (cc1 < NCC) {  // write prefetched chunk to LDS
      const bool limb_lo = (cc1 < NCH);
#pragma unroll
      for (int it = 0; it < 5; ++it) {
        const int s = tid + it * THREADS;
        const int n = s >> 2, q = s & 3;
        *(half8*)(SB + BOFF + n * 64 + ((q ^ (n & 3)) << 4)) = bpre[it];
      }
      half4 a4;
#pragma unroll
      for (int k = 0; k < 4; ++k) {
        const float vk = ((const float*)&xpre)[k];
        const _Float16 hk = (_Float16)vk;
        a4[k] = limb_lo ? (_Float16)((vk - (float)hk) * 2048.0f) : hk;
      }
      *(half4*)(SB + AOFF + arow * 64 + ((aq ^ (arow & 3)) << 4) + ah * 8) = a4;
      __syncthreads();
    }
  }

  // ---- phase 2: per-row softmax / argmax / gather via 16-row LDS slabs ----
  float bfrag[5];
#pragma unroll
  for (int t = 0; t < 5; ++t) bfrag[t] = bias[wvn * 160 + t * 32 + lo];

  float racc[G_][5];
#pragma unroll
  for (int g = 0; g < G_; ++g)
#pragma unroll
    for (int j = 0; j < 5; ++j) racc[g][j] = 0.f;

  float* LBUF = (float*)SB;  // [16][640]

#pragma unroll
  for (int R = 0; R < 4; ++R) {
    // writers: waves with wvm==R>>1 dump regs 8*(R&1)..+7 (C/D layout:
    // col=lane&31, row=(reg&3)+8*(reg>>2)+4*hi) -> rows 16R..16R+15
    if (wvm == (R >> 1)) {
#pragma unroll
      for (int t = 0; t < 5; ++t) {
        const int col = wvn * 160 + t * 32 + lo;
#pragma unroll
        for (int rr = 0; rr < 8; ++rr) {
          const int reg  = ((R & 1) << 3) + rr;
          const int lrow = (rr & 3) + ((rr >> 2) << 3) + (hi << 2);
          LBUF[lrow * GV + col] = acc[t][reg] + bfrag[t];
        }
      }
    }
    __syncthreads();
#pragma unroll
    for (int rr2 = 0; rr2 < 2; ++rr2) {
      const int lrow = wv * 2 + rr2;
      const int n = n0 + R * 16 + lrow;
#pragma unroll
      for (int g = 0; g < G_; ++g) {
        float L[5], GU[5];
#pragma unroll
        for (int j = 0; j < 5; ++j) {
          L[j]  = LBUF[lrow * GV + g * V_ + 64 * j + ln];
          GU[j] = gum[(size_t)n * GV + g * V_ + 64 * j + ln];
        }
        // local max/argmax (cols ascend with j -> first-occurrence tie-break)
        float m1 = L[0];         int a1 = ln;
        float m2 = L[0] + GU[0]; int a2 = ln;
#pragma unroll
        for (int j = 1; j < 5; ++j) {
          const int cix = 64 * j + ln;
          if (L[j] > m1) { m1 = L[j]; a1 = cix; }
          const float t2 = L[j] + GU[j];
          if (t2 > m2) { m2 = t2; a2 = cix; }
        }
        // wave reduce (prefer smaller index on exact ties)
        for (int off = 32; off; off >>= 1) {
          float om = __shfl_down(m1, off); int oa = __shfl_down(a1, off);
          if (om > m1 || (om == m1 && oa < a1)) { m1 = om; a1 = oa; }
          float om2 = __shfl_down(m2, off); int oa2 = __shfl_down(a2, off);
          if (om2 > m2 || (om2 == m2 && oa2 < a2)) { m2 = om2; a2 = oa2; }
        }
        m1 = __shfl(m1, 0); a1 = __shfl(a1, 0); a2 = __shfl(a2, 0);

        // softmax (no tau) for avg_probs
        float e[5], s = 0.f;
#pragma unroll
        for (int j = 0; j < 5; ++j) { e[j] = expf(L[j] - m1); s += e[j]; }
        for (int off = 32; off; off >>= 1) s += __shfl_down(s, off);
        s = __shfl(s, 0);
        const float inv = 1.0f / s;
#pragma unroll
        for (int j = 0; j < 5; ++j) racc[g][j] += e[j] * inv;

        if (ln == 0) {
          const int t = n & (T_ - 1);
          // packed 16-bit histogram bump (count <= 16, no carry possible)
          atomicAdd(&counts[(t * G_ + g) * (V_ / 2) + (a1 >> 1)],
                    1u << ((a1 & 1) * 16));
        }
        // quantized[n, g*D : (g+1)*D] = codebook[g, a2, :]
        const float2* cbr = (const float2*)(cb + (size_t)(g * V_ + a2) * D_);
        float2* op = (float2*)(out + (size_t)n * (G_ * D_) + g * D_);
        op[ln] = cbr[ln];
      }
    }
    __syncthreads();
  }

  // ---- block-level avg_probs partial: reduce 8 wave-private copies ----
  float* la = (float*)SB;  // [8][GV] = 20480 B
#pragma unroll
  for (int g = 0; g < G_; ++g)
#pragma unroll
    for (int j = 0; j < 5; ++j)
      la[wv * GV + g * V_ + 64 * j + ln] = racc[g][j];
  __syncthreads();
  for (int cix = tid; cix < GV; cix += THREADS) {
    float s = 0.f;
#pragma unroll
    for (int v = 0; v < 8; ++v) s += la[v * GV + cix];
    avg_part[(size_t)blk * GV + cix] = s;
  }
}

// Per-(t,g) hard-histogram entropy -> exp(-H). One wave per item.
// counts are packed u32 (2 x u16 fields): 160 words per item.
__global__ __launch_bounds__(256) void k_code_ent(
    const unsigned* __restrict__ counts, float* __restrict__ ent)
{
  const int item = blockIdx.x * 4 + (threadIdx.x >> 6);  // 0..2047
  const int lane = threadIdx.x & 63;
  const unsigned* c = counts + (size_t)item * (V_ / 2);
  float s = 0.f;
#pragma unroll
  for (int j = 0; j < 3; ++j) {
    const int wi = lane + 64 * j;
    if (wi < V_ / 2) {
      const unsigned wd = c[wi];
      const float h0 = (float)(wd & 0xffffu) * (1.0f / B_);
      const float h1 = (float)(wd >> 16) * (1.0f / B_);
      s += h0 * logf(h0 + EPS_) + h1 * logf(h1 + EPS_);
    }
  }
  for (int off = 32; off; off >>= 1) s += __shfl_down(s, off);
  if (lane == 0) ent[item] = expf(-s);
}

// Column-parallel reduce of avg_part (NBLK x 640) -> avgred (640).
__global__ __launch_bounds__(64) void k_avg_red(
    const float* __restrict__ avg_part, float* __restrict__ avgred)
{
  const int cix = blockIdx.x;           // 0..639
  const int lane = threadIdx.x;         // 0..63
  float s = 0.f;
  for (int b = lane; b < NBLK; b += 64) s += avg_part[(size_t)b * GV + cix];
  for (int off = 32; off; off >>= 1) s += __shfl_down(s, off);
  if (lane == 0) avgred[cix] = s;
}

// Finalize both scalars. Single block of 640 threads.
__global__ __launch_bounds__(GV) void k_final(
    const float* __restrict__ avgred, const float* __restrict__ ent,
    float* __restrict__ out2)
{
  __shared__ float sh[GV];   // p*log(p+eps) per column
  __shared__ float shc[GV];  // code-entropy partials
  const int tid = threadIdx.x;

  const float p = avgred[tid] * (1.0f / N_);
  sh[tid] = p * logf(p + EPS_);

  float cs = 0.f;
  for (int i = tid; i < T_ * G_; i += GV) cs += ent[i];
  shc[tid] = cs;
  __syncthreads();

  if (tid < 64) {
    float s0 = 0.f, s1 = 0.f, sc = 0.f;
    for (int j = tid; j < V_; j += 64) { s0 += sh[j]; s1 += sh[V_ + j]; }
    for (int j = tid; j < GV; j += 64) sc += shc[j];
    for (int off = 32; off; off >>= 1) {
      s0 += __shfl_down(s0, off);
      s1 += __shfl_down(s1, off);
      sc += __shfl_down(sc, off);
    }
    if (tid == 0) {
      out2[0] = sc;                          // code_perplexity
      out2[1] = expf(-s0) + expf(-s1);       // prob_perplexity
    }
  }
}

extern "C" void kernel_launch(void* const* d_in, const int* in_sizes, int n_in,
                              void* d_out, int out_size, void* d_ws, size_t ws_size,
                              hipStream_t stream) {
  const float* x   = (const float*)d_in[0];  // (B,T,F)
  const float* w   = (const float*)d_in[1];  // (G*V, F)
  const float* b   = (const float*)d_in[2];  // (G*V,)
  const float* cb  = (const float*)d_in[3];  // (1, G*V, D)
  const float* gum = (const float*)d_in[4];  // (B*T, G, V)
  float* out = (float*)d_out;                // quantized (N*G*D) ++ [code_ppl, prob_ppl]
  float* ws  = (float*)d_ws;

  unsigned* counts = (unsigned*)(ws + WS_COUNTS);
  float* avgp   = ws + WS_AVG;
  float* ent    = ws + WS_ENT;
  _Float16* whp = (_Float16*)(ws + WS_WH);
  _Float16* wlp = (_Float16*)(ws + WS_WL);
  float* avgred = (float*)counts;  // reuse: counts dead after k_code_ent

  hipMemsetAsync(counts, 0, (size_t)CNTW * sizeof(unsigned), stream);
  k_conv_w<<<(GV * F_ / 4) / 512, 512, 0, stream>>>(w, whp, wlp);
  k_fused<<<NBLK, THREADS, 0, stream>>>(x, whp, wlp, b, cb, gum, out, counts, avgp);
  k_code_ent<<<(T_ * G_) / 4, 256, 0, stream>>>(counts, ent);
  k_avg_red<<<GV, 64, 0, stream>>>(avgp, avgred);
  k_final<<<1, GV, 0, stream>>>(avgred, ent, out + (size_t)N_ * G_ * D_);
}

// Round 3
// 195.649 us; speedup vs baseline: 1.7991x; 1.1545x over previous
//
#include <hip/hip_runtime.h>
#include <math.h>

// Problem constants (match reference)
#define B_   16
#define T_   1024
#define F_   512
#define G_   2
#define V_   320
#define D_   128
#define N_   (B_ * T_)      // 16384 tokens
#define GV   (G_ * V_)      // 640
#define EPS_ 1e-7f

// Fused-GEMM config: 3-pass f16 limb-split MFMA
//   logits = xh*wh + 2^-11*(xh*wl' + xl'*wh),  xl' = f16((x - f16(x))*2048)
#define ROWS    64
#define THREADS 512          // 8 waves: 2(M) x 4(N) wave grid, wave tile 32x160
#define NBLK    (N_ / ROWS)  // 256 blocks -> 1 block/CU, grid fully resident
#define CHK     32           // k elems (f16) staged per chunk
#define NCH     (F_ / CHK)   // 16 chunks per pass
#define NCC     (3 * NCH)    // 48 chunks total: lh, hl, hh passes

// LDS: double-buffered. Per buffer: B tile 640x32 f16 (40960 B, 64 B/row)
// + A tile 64x32 f16 (4096 B). Swizzle: quad ^= (row>>1)&3  (NOT row&3 --
// row stride is 64 B = half the 128 B bank span, so same-parity rows need
// the XOR to vary with row>>1 to spread quarter-wave reads over all slots).
#define BOFF  0
#define AOFF  40960
#define BUFSZ 45056
#define LDSZ  (2 * BUFSZ)    // 90112 B -> 1 block/CU

typedef _Float16 half8 __attribute__((ext_vector_type(8)));
typedef _Float16 half4 __attribute__((ext_vector_type(4)));
typedef float f32x16 __attribute__((ext_vector_type(16)));

// Workspace layout (float slots). counts PACKED u32 (2 x u16, count<=16).
// Total 821888 floats = 3.29 MB, under the 3.94 MB proven-safe footprint.
#define CNTW      (T_ * G_ * (V_ / 2))      // 327680 u32 words
#define WS_COUNTS 0
#define WS_AVG    CNTW                      // NBLK*GV = 163840
#define WS_ENT    (WS_AVG + NBLK * GV)      // T_*G_   = 2048
#define WS_WH     (WS_ENT + T_ * G_)        // GV*F_ f16 = 163840 float slots
#define WS_WL     (WS_WH + (GV * F_ / 2))   // GV*F_ f16 = 163840 float slots
#define WS_AVGRED (WS_WL + (GV * F_ / 2))   // 640 (separate: k_post races alias)

// ---- w -> (wh, wl') f16 limbs, [GV][F_] row-major ----
__global__ __launch_bounds__(512) void k_conv_w(
    const float* __restrict__ w, _Float16* __restrict__ wh, _Float16* __restrict__ wl)
{
  const int i = blockIdx.x * 512 + threadIdx.x;  // 81920 float4s
  const float4 v = ((const float4*)w)[i];
  half4 h, l;
#pragma unroll
  for (int k = 0; k < 4; ++k) {
    const float vk = ((const float*)&v)[k];
    const _Float16 hk = (_Float16)vk;
    h[k] = hk;
    l[k] = (_Float16)((vk - (float)hk) * 2048.0f);
  }
  ((half4*)wh)[i] = h;
  ((half4*)wl)[i] = l;
}

// Fused: 3-pass limb-split MFMA GEMM + softmax stats + argmaxes + gather.
__global__ __launch_bounds__(THREADS, 1) void k_fused(
    const float* __restrict__ x, const _Float16* __restrict__ wh,
    const _Float16* __restrict__ wl, const float* __restrict__ bias,
    const float* __restrict__ cb, const float* __restrict__ gum,
    float* __restrict__ out, unsigned* __restrict__ counts,
    float* __restrict__ avg_part)
{
  __shared__ __align__(16) unsigned char SB[LDSZ];
  const int tid = threadIdx.x;
  const int wv  = tid >> 6;           // 0..7
  const int ln  = tid & 63;
  const int lo  = ln & 31, hi = ln >> 5;
  const int wvm = wv >> 2, wvn = wv & 3;
  const int blk = blockIdx.x;
  const int n0  = blk * ROWS;

  f32x16 acc[5];
#pragma unroll
  for (int t = 0; t < 5; ++t)
#pragma unroll
    for (int i = 0; i < 16; ++i) acc[t][i] = 0.0f;

  // staging slot assignment
  const int arow = tid >> 3, asub = tid & 7;   // A: 64 rows x 8 float4-slots
  const int aq = asub >> 1, ah = asub & 1;
  const float4* x4f = (const float4*)x;

  // hoisted fragment read addresses (loop-invariant; swizzle q ^= (row>>1)&3)
  int aaddr[2], baddr[5][2];
  {
    const int ar = wvm * 32 + lo;
#pragma unroll
    for (int ks = 0; ks < 2; ++ks)
      aaddr[ks] = AOFF + ar * 64 + (((2 * ks + hi) ^ ((ar >> 1) & 3)) << 4);
#pragma unroll
    for (int t = 0; t < 5; ++t) {
      const int bn = wvn * 160 + t * 32 + lo;
#pragma unroll
      for (int ks = 0; ks < 2; ++ks)
        baddr[t][ks] = BOFF + bn * 64 + (((2 * ks + hi) ^ ((bn >> 1) & 3)) << 4);
    }
  }

  half8 bpre[5];
  float4 xpre;

  // ---- prologue: stage chunk 0 into buf0, prefetch chunk 1 ----
#pragma unroll
  for (int it = 0; it < 5; ++it) {
    const int s = tid + it * THREADS;
    const int n = s >> 2, q = s & 3;
    bpre[it] = ((const half8*)wh)[n * 64 + q];
  }
  xpre = x4f[(size_t)(n0 + arow) * (F_ / 4) + asub];
  {
#pragma unroll
    for (int it = 0; it < 5; ++it) {
      const int s = tid + it * THREADS;
      const int n = s >> 2, q = s & 3;
      *(half8*)(SB + BOFF + n * 64 + ((q ^ ((n >> 1) & 3)) << 4)) = bpre[it];
    }
    half4 a4;
#pragma unroll
    for (int k = 0; k < 4; ++k) {
      const float vk = ((const float*)&xpre)[k];
      const _Float16 hk = (_Float16)vk;
      a4[k] = (_Float16)((vk - (float)hk) * 2048.0f);   // low limb, pass lh
    }
    *(half4*)(SB + AOFF + arow * 64 + ((aq ^ ((arow >> 1) & 3)) << 4) + ah * 8) = a4;
  }
  {  // prefetch chunk 1 (still pass lh: B=wh)
#pragma unroll
    for (int it = 0; it < 5; ++it) {
      const int s = tid + it * THREADS;
      const int n = s >> 2, q = s & 3;
      bpre[it] = ((const half8*)wh)[n * 64 + 4 + q];
    }
    xpre = x4f[(size_t)(n0 + arow) * (F_ / 4) + 8 + asub];
  }
  __builtin_amdgcn_sched_barrier(0);
  asm volatile("s_waitcnt lgkmcnt(0)" ::: "memory");
  __builtin_amdgcn_s_barrier();
  __builtin_amdgcn_sched_barrier(0);

  // ---- main loop: 48 chunks, double-buffered, ONE barrier per chunk.
  // Raw lgkmcnt(0)+s_barrier (no vmcnt drain): chunk c+2's global loads stay
  // in flight across the barrier; their ds_write next iter waits via the
  // compiler's register-dependency vmcnt. ----
  for (int cc = 0; cc < NCC; ++cc) {
    const int p = cc & 1;
    unsigned char* curb = SB + p * BUFSZ;
    unsigned char* nxtb = SB + (p ^ 1) * BUFSZ;
    if (cc + 1 < NCC) {  // write prefetched chunk cc+1 into the other buffer
      const bool limb_lo = (cc + 1 < NCH);
#pragma unroll
      for (int it = 0; it < 5; ++it) {
        const int s = tid + it * THREADS;
        const int n = s >> 2, q = s & 3;
        *(half8*)(nxtb + BOFF + n * 64 + ((q ^ ((n >> 1) & 3)) << 4)) = bpre[it];
      }
      half4 a4;
#pragma unroll
      for (int k = 0; k < 4; ++k) {
        const float vk = ((const float*)&xpre)[k];
        const _Float16 hk = (_Float16)vk;
        a4[k] = limb_lo ? (_Float16)((vk - (float)hk) * 2048.0f) : hk;
      }
      *(half4*)(nxtb + AOFF + arow * 64 + ((aq ^ ((arow >> 1) & 3)) << 4) + ah * 8) = a4;
    }
    if (cc + 2 < NCC) {  // prefetch chunk cc+2 into registers
      const int c2 = cc + 2;
      const _Float16* bs = ((c2 >> 4) == 1) ? wl : wh;
      const int k08 = (c2 & 15) * 4;
#pragma unroll
      for (int it = 0; it < 5; ++it) {
        const int s = tid + it * THREADS;
        const int n = s >> 2, q = s & 3;
        bpre[it] = ((const half8*)bs)[n * 64 + k08 + q];
      }
      xpre = x4f[(size_t)(n0 + arow) * (F_ / 4) + (c2 & 15) * 8 + asub];
    }
    // compute current chunk from curb
#pragma unroll
    for (int ks = 0; ks < 2; ++ks) {
      const half8 af = *(const half8*)(curb + aaddr[ks]);
#pragma unroll
      for (int t = 0; t < 5; ++t) {
        const half8 bf = *(const half8*)(curb + baddr[t][ks]);
        acc[t] = __builtin_amdgcn_mfma_f32_32x32x16_f16(af, bf, acc[t], 0, 0, 0);
      }
    }
    if (cc == 2 * NCH - 1) {  // finished lh+hl: scale the low-limb partial
#pragma unroll
      for (int t = 0; t < 5; ++t)
#pragma unroll
        for (int i = 0; i < 16; ++i) acc[t][i] *= (1.0f / 2048.0f);
    }
    __builtin_amdgcn_sched_barrier(0);
    asm volatile("s_waitcnt lgkmcnt(0)" ::: "memory");
    __builtin_amdgcn_s_barrier();
    __builtin_amdgcn_sched_barrier(0);
  }

  // ---- phase 2: per-row softmax / argmax / gather via 16-row LDS slabs ----
  float bfrag[5];
#pragma unroll
  for (int t = 0; t < 5; ++t) bfrag[t] = bias[wvn * 160 + t * 32 + lo];

  float racc[G_][5];
#pragma unroll
  for (int g = 0; g < G_; ++g)
#pragma unroll
    for (int j = 0; j < 5; ++j) racc[g][j] = 0.f;

  float* LBUF = (float*)SB;  // [16][640] (buf0 region; safe after final barrier)

#pragma unroll
  for (int R = 0; R < 4; ++R) {
    // writers: waves with wvm==R>>1 dump regs 8*(R&1)..+7 (C/D layout:
    // col=lane&31, row=(reg&3)+8*(reg>>2)+4*hi) -> rows 16R..16R+15
    if (wvm == (R >> 1)) {
#pragma unroll
      for (int t = 0; t < 5; ++t) {
        const int col = wvn * 160 + t * 32 + lo;
#pragma unroll
        for (int rr = 0; rr < 8; ++rr) {
          const int reg  = ((R & 1) << 3) + rr;
          const int lrow = (rr & 3) + ((rr >> 2) << 3) + (hi << 2);
          LBUF[lrow * GV + col] = acc[t][reg] + bfrag[t];
        }
      }
    }
    __syncthreads();
#pragma unroll
    for (int rr2 = 0; rr2 < 2; ++rr2) {
      const int lrow = wv * 2 + rr2;
      const int n = n0 + R * 16 + lrow;
#pragma unroll
      for (int g = 0; g < G_; ++g) {
        float L[5], GU[5];
#pragma unroll
        for (int j = 0; j < 5; ++j) {
          L[j]  = LBUF[lrow * GV + g * V_ + 64 * j + ln];
          GU[j] = gum[(size_t)n * GV + g * V_ + 64 * j + ln];
        }
        // local max/argmax (cols ascend with j -> first-occurrence tie-break)
        float m1 = L[0];         int a1 = ln;
        float m2 = L[0] + GU[0]; int a2 = ln;
#pragma unroll
        for (int j = 1; j < 5; ++j) {
          const int cix = 64 * j + ln;
          if (L[j] > m1) { m1 = L[j]; a1 = cix; }
          const float t2 = L[j] + GU[j];
          if (t2 > m2) { m2 = t2; a2 = cix; }
        }
        // wave reduce (prefer smaller index on exact ties)
        for (int off = 32; off; off >>= 1) {
          float om = __shfl_down(m1, off); int oa = __shfl_down(a1, off);
          if (om > m1 || (om == m1 && oa < a1)) { m1 = om; a1 = oa; }
          float om2 = __shfl_down(m2, off); int oa2 = __shfl_down(a2, off);
          if (om2 > m2 || (om2 == m2 && oa2 < a2)) { m2 = om2; a2 = oa2; }
        }
        m1 = __shfl(m1, 0); a1 = __shfl(a1, 0); a2 = __shfl(a2, 0);

        // softmax (no tau) for avg_probs
        float e[5], s = 0.f;
#pragma unroll
        for (int j = 0; j < 5; ++j) { e[j] = expf(L[j] - m1); s += e[j]; }
        for (int off = 32; off; off >>= 1) s += __shfl_down(s, off);
        s = __shfl(s, 0);
        const float inv = 1.0f / s;
#pragma unroll
        for (int j = 0; j < 5; ++j) racc[g][j] += e[j] * inv;

        if (ln == 0) {
          const int t = n & (T_ - 1);
          // packed 16-bit histogram bump (count <= 16, no carry possible)
          atomicAdd(&counts[(t * G_ + g) * (V_ / 2) + (a1 >> 1)],
                    1u << ((a1 & 1) * 16));
        }
        // quantized[n, g*D : (g+1)*D] = codebook[g, a2, :]
        const float2* cbr = (const float2*)(cb + (size_t)(g * V_ + a2) * D_);
        float2* op = (float2*)(out + (size_t)n * (G_ * D_) + g * D_);
        op[ln] = cbr[ln];
      }
    }
    __syncthreads();
  }

  // ---- block-level avg_probs partial: reduce 8 wave-private copies ----
  float* la = (float*)SB;  // [8][GV] = 20480 B
#pragma unroll
  for (int g = 0; g < G_; ++g)
#pragma unroll
    for (int j = 0; j < 5; ++j)
      la[wv * GV + g * V_ + 64 * j + ln] = racc[g][j];
  __syncthreads();
  for (int cix = tid; cix < GV; cix += THREADS) {
    float s = 0.f;
#pragma unroll
    for (int v = 0; v < 8; ++v) s += la[v * GV + cix];
    avg_part[(size_t)blk * GV + cix] = s;
  }
}

// Merged post-pass (one launch): blocks 0..511 = per-(t,g) histogram entropy;
// blocks 512..671 = column reduce of avg_part -> avgred (separate ws slot,
// NOT aliasing counts -- both halves run concurrently).
__global__ __launch_bounds__(256) void k_post(
    const unsigned* __restrict__ counts, float* __restrict__ ent,
    const float* __restrict__ avg_part, float* __restrict__ avgred)
{
  const int b = blockIdx.x;
  const int lane = threadIdx.x & 63;
  if (b < (T_ * G_) / 4) {
    const int item = b * 4 + (threadIdx.x >> 6);  // 0..2047
    const unsigned* c = counts + (size_t)item * (V_ / 2);
    float s = 0.f;
#pragma unroll
    for (int j = 0; j < 3; ++j) {
      const int wi = lane + 64 * j;
      if (wi < V_ / 2) {
        const unsigned wd = c[wi];
        const float h0 = (float)(wd & 0xffffu) * (1.0f / B_);
        const float h1 = (float)(wd >> 16) * (1.0f / B_);
        s += h0 * logf(h0 + EPS_) + h1 * logf(h1 + EPS_);
      }
    }
    for (int off = 32; off; off >>= 1) s += __shfl_down(s, off);
    if (lane == 0) ent[item] = expf(-s);
  } else {
    const int cix = (b - (T_ * G_) / 4) * 4 + (threadIdx.x >> 6);  // 0..639
    float s = 0.f;
    for (int bb = lane; bb < NBLK; bb += 64) s += avg_part[(size_t)bb * GV + cix];
    for (int off = 32; off; off >>= 1) s += __shfl_down(s, off);
    if (lane == 0) avgred[cix] = s;
  }
}

// Finalize both scalars. Single block of 640 threads.
__global__ __launch_bounds__(GV) void k_final(
    const float* __restrict__ avgred, const float* __restrict__ ent,
    float* __restrict__ out2)
{
  __shared__ float sh[GV];   // p*log(p+eps) per column
  __shared__ float shc[GV];  // code-entropy partials
  const int tid = threadIdx.x;

  const float p = avgred[tid] * (1.0f / N_);
  sh[tid] = p * logf(p + EPS_);

  float cs = 0.f;
  for (int i = tid; i < T_ * G_; i += GV) cs += ent[i];
  shc[tid] = cs;
  __syncthreads();

  if (tid < 64) {
    float s0 = 0.f, s1 = 0.f, sc = 0.f;
    for (int j = tid; j < V_; j += 64) { s0 += sh[j]; s1 += sh[V_ + j]; }
    for (int j = tid; j < GV; j += 64) sc += shc[j];
    for (int off = 32; off; off >>= 1) {
      s0 += __shfl_down(s0, off);
      s1 += __shfl_down(s1, off);
      sc += __shfl_down(sc, off);
    }
    if (tid == 0) {
      out2[0] = sc;                          // code_perplexity
      out2[1] = expf(-s0) + expf(-s1);       // prob_perplexity
    }
  }
}

extern "C" void kernel_launch(void* const* d_in, const int* in_sizes, int n_in,
                              void* d_out, int out_size, void* d_ws, size_t ws_size,
                              hipStream_t stream) {
  const float* x   = (const float*)d_in[0];  // (B,T,F)
  const float* w   = (const float*)d_in[1];  // (G*V, F)
  const float* b   = (const float*)d_in[2];  // (G*V,)
  const float* cb  = (const float*)d_in[3];  // (1, G*V, D)
  const float* gum = (const float*)d_in[4];  // (B*T, G, V)
  float* out = (float*)d_out;                // quantized (N*G*D) ++ [code_ppl, prob_ppl]
  float* ws  = (float*)d_ws;

  unsigned* counts = (unsigned*)(ws + WS_COUNTS);
  float* avgp   = ws + WS_AVG;
  float* ent    = ws + WS_ENT;
  _Float16* whp = (_Float16*)(ws + WS_WH);
  _Float16* wlp = (_Float16*)(ws + WS_WL);
  float* avgred = ws + WS_AVGRED;

  hipMemsetAsync(counts, 0, (size_t)CNTW * sizeof(unsigned), stream);
  k_conv_w<<<(GV * F_ / 4) / 512, 512, 0, stream>>>(w, whp, wlp);
  k_fused<<<NBLK, THREADS, 0, stream>>>(x, whp, wlp, b, cb, gum, out, counts, avgp);
  k_post<<<(T_ * G_) / 4 + GV / 4, 256, 0, stream>>>(counts, ent, avgp, avgred);
  k_final<<<1, GV, 0, stream>>>(avgred, ent, out + (size_t)N_ * G_ * D_);
}

// Round 4
// 188.568 us; speedup vs baseline: 1.8666x; 1.0376x over previous
//
#include <hip/hip_runtime.h>
#include <math.h>

// Problem constants (match reference)
#define B_   16
#define T_   1024
#define F_   512
#define G_   2
#define V_   320
#define D_   128
#define N_   (B_ * T_)      // 16384 tokens
#define GV   (G_ * V_)      // 640
#define EPS_ 1e-7f

// Fused-GEMM: single K-sweep, dual-limb f16 MFMA
//   logits = xh*wh + 2^-11*(xl*wh + xh*wl),  xl = f16((x - f16(x))*2048)
#define ROWS    64
#define THREADS 512          // 8 waves: 2(M) x 4(N) wave grid, wave tile 32x160
#define NBLK    (N_ / ROWS)  // 256 blocks -> 1 block/CU
#define NC      32           // K=16 per chunk, 32 chunks

// LDS per buffer: B = 2 limbs x 20 frag-groups x 1KB = 40960 B (fragment-linear),
// A = 2 limbs x 2 mg x 1KB = 4096 B. Double-buffered: 88 KB.
#define BOFF  0
#define AOFF  40960
#define BUFSZ 45056
#define LDSZ  (2 * BUFSZ)

typedef _Float16 half8 __attribute__((ext_vector_type(8)));
typedef _Float16 half2_t __attribute__((ext_vector_type(2)));
typedef float f32x16 __attribute__((ext_vector_type(16)));

#define GLDS16(g, l)                                                           \
  __builtin_amdgcn_global_load_lds(                                            \
      (const __attribute__((address_space(1))) unsigned int*)(g),              \
      (__attribute__((address_space(3))) unsigned int*)(l), 16, 0, 0)

// Workspace layout (float slots). counts PACKED u32 (2 x u16, count<=16).
// Total 821888 floats = 3.29 MB (same as R3 proven footprint).
#define CNTW      (T_ * G_ * (V_ / 2))      // 327680 u32 words
#define WS_COUNTS 0
#define WS_AVG    CNTW                      // NBLK*GV = 163840
#define WS_ENT    (WS_AVG + NBLK * GV)      // T_*G_   = 2048
#define WS_WPK    (WS_ENT + T_ * G_)        // packed w limbs: 655360 halves
#define WS_AVGRED (WS_WPK + (GV * F_ * 2 / 2))

// ---- w -> packed fragment-order f16 limbs ----
// wpk half8 index: ((c*2 + limb)*20 + n)*64 + ln
//   contents: w[n*32 + (ln&31)][c*16 + (ln>>5)*8 + j] limb-converted.
// One block per (c,limb); fragment groups are 1 KB lane-linear.
__global__ __launch_bounds__(640) void k_conv_w(
    const float* __restrict__ w, _Float16* __restrict__ wpk)
{
  const int cl = blockIdx.x;     // 0..63 = c*2 + limb
  const int c = cl >> 1, limb = cl & 1;
#pragma unroll
  for (int it = 0; it < 2; ++it) {
    const int t2 = threadIdx.x + it * 640;   // 0..1279
    const int n = t2 >> 6, ln = t2 & 63;
    const int row = n * 32 + (ln & 31);
    const int k0 = c * 16 + (ln >> 5) * 8;
    const float4 v0 = *(const float4*)(w + (size_t)row * F_ + k0);
    const float4 v1 = *(const float4*)(w + (size_t)row * F_ + k0 + 4);
    half8 h;
#pragma unroll
    for (int k = 0; k < 8; ++k) {
      const float vk = (k < 4) ? ((const float*)&v0)[k] : ((const float*)&v1)[k - 4];
      const _Float16 hk = (_Float16)vk;
      h[k] = limb ? (_Float16)((vk - (float)hk) * 2048.0f) : hk;
    }
    ((half8*)wpk)[((size_t)cl * 20 + n) * 64 + ln] = h;
  }
}

// Fused: dual-limb MFMA GEMM + softmax stats + argmaxes + gather.
__global__ __launch_bounds__(THREADS, 2) void k_fused(
    const float* __restrict__ x, const _Float16* __restrict__ wpk,
    const float* __restrict__ bias, const float* __restrict__ cb,
    const float* __restrict__ gum, float* __restrict__ out,
    unsigned* __restrict__ counts, float* __restrict__ avg_part)
{
  __shared__ __align__(16) unsigned char SB[LDSZ];
  const int tid = threadIdx.x;
  const int wv  = tid >> 6;           // 0..7
  const int ln  = tid & 63;
  const int lo  = ln & 31, hi = ln >> 5;
  const int wvm = wv >> 2, wvn = wv & 3;
  const int blk = blockIdx.x;
  const int n0  = blk * ROWS;

  f32x16 ah_acc[5], al_acc[5];
#pragma unroll
  for (int t = 0; t < 5; ++t)
#pragma unroll
    for (int i = 0; i < 16; ++i) { ah_acc[t][i] = 0.0f; al_acc[t][i] = 0.0f; }

  // A staging mapping: thread -> (row, k-pair); one float2 of x per chunk.
  const int arow = tid >> 3;          // 0..63
  const int akp  = tid & 7;           // k-pair within 16-k chunk
  const int awoff = (arow >> 5) * 1024 + (((akp >> 2) << 5) + (arow & 31)) * 16
                  + (akp & 3) * 4;    // within-limb offset; limb stride 2048
  const float2* x2 = (const float2*)x;
  const size_t xrowbase = (size_t)(n0 + arow) * (F_ / 2) + akp;

  // fragment read offsets (all lane-linear, conflict-free)
  const int aro_h = AOFF + 0 * 2048 + wvm * 1024 + ln * 16;
  const int aro_l = AOFF + 1 * 2048 + wvm * 1024 + ln * 16;
  int bro_h[5], bro_l[5];
#pragma unroll
  for (int t = 0; t < 5; ++t) {
    bro_h[t] = BOFF + (0 * 20 + wvn * 5 + t) * 1024 + ln * 16;
    bro_l[t] = BOFF + (1 * 20 + wvn * 5 + t) * 1024 + ln * 16;
  }

  // ---- prologue: stage chunk 0 into buf0 ----
  {
    const float2 xv = x2[xrowbase + 0 * 8];            // x first (oldest vmem)
#pragma unroll
    for (int i = 0; i < 5; ++i) {
      const int seg = wv * 5 + i;                       // = limb*20 + n group
      GLDS16(wpk + ((size_t)(0 * 40 + seg) * 64 + ln) * 8, SB + BOFF + seg * 1024);
    }
    half2_t hh, hl;
#pragma unroll
    for (int k = 0; k < 2; ++k) {
      const float f = k ? xv.y : xv.x;
      const _Float16 h = (_Float16)f;
      hh[k] = h; hl[k] = (_Float16)((f - (float)h) * 2048.0f);
    }
    *(half2_t*)(SB + AOFF + awoff) = hh;
    *(half2_t*)(SB + AOFF + 2048 + awoff) = hl;
  }
  __builtin_amdgcn_sched_barrier(0);
  asm volatile("s_waitcnt vmcnt(0) lgkmcnt(0)" ::: "memory");
  __builtin_amdgcn_s_barrier();
  __builtin_amdgcn_sched_barrier(0);

  // ---- main loop: 32 chunks, double-buffered, one barrier per chunk ----
  for (int cc = 0; cc < NC; ++cc) {
    unsigned char* curb = SB + (cc & 1) * BUFSZ;
    unsigned char* nxtb = SB + ((cc & 1) ^ 1) * BUFSZ;
    if (cc + 1 < NC) {  // stage chunk cc+1 into nxtb (read-finished last chunk)
      const int c1 = cc + 1;
      const float2 xv = x2[xrowbase + c1 * 8];          // issue x FIRST
#pragma unroll
      for (int i = 0; i < 5; ++i) {
        const int seg = wv * 5 + i;
        GLDS16(wpk + ((size_t)(c1 * 40 + seg) * 64 + ln) * 8,
               nxtb + BOFF + seg * 1024);
      }
      half2_t hh, hl;                                   // compiler waits x here
#pragma unroll
      for (int k = 0; k < 2; ++k) {
        const float f = k ? xv.y : xv.x;
        const _Float16 h = (_Float16)f;
        hh[k] = h; hl[k] = (_Float16)((f - (float)h) * 2048.0f);
      }
      *(half2_t*)(nxtb + AOFF + awoff) = hh;
      *(half2_t*)(nxtb + AOFF + 2048 + awoff) = hl;
    }
    // compute current chunk (all reads lane-linear)
    const half8 ah = *(const half8*)(curb + aro_h);
    const half8 al = *(const half8*)(curb + aro_l);
#pragma unroll
    for (int t = 0; t < 5; ++t) {
      const half8 bh = *(const half8*)(curb + bro_h[t]);
      const half8 bl = *(const half8*)(curb + bro_l[t]);
      ah_acc[t] = __builtin_amdgcn_mfma_f32_32x32x16_f16(ah, bh, ah_acc[t], 0, 0, 0);
      al_acc[t] = __builtin_amdgcn_mfma_f32_32x32x16_f16(al, bh, al_acc[t], 0, 0, 0);
      al_acc[t] = __builtin_amdgcn_mfma_f32_32x32x16_f16(ah, bl, al_acc[t], 0, 0, 0);
    }
    __builtin_amdgcn_sched_barrier(0);
    asm volatile("s_waitcnt vmcnt(0) lgkmcnt(0)" ::: "memory");
    __builtin_amdgcn_s_barrier();
    __builtin_amdgcn_sched_barrier(0);
  }

  // ---- phase 2: per-row softmax / argmax / gather via 16-row LDS slabs ----
  float bfrag[5];
#pragma unroll
  for (int t = 0; t < 5; ++t) bfrag[t] = bias[wvn * 160 + t * 32 + lo];

  float racc[G_][5];
#pragma unroll
  for (int g = 0; g < G_; ++g)
#pragma unroll
    for (int j = 0; j < 5; ++j) racc[g][j] = 0.f;

  float* LBUF = (float*)SB;  // [16][640] = 40 KB

#pragma unroll
  for (int R = 0; R < 4; ++R) {
    // writers: waves with wvm==R>>1 dump regs 8*(R&1)..+7 (C/D layout:
    // col=lane&31, row=(reg&3)+8*(reg>>2)+4*hi) -> rows 16R..16R+15
    if (wvm == (R >> 1)) {
#pragma unroll
      for (int t = 0; t < 5; ++t) {
        const int col = wvn * 160 + t * 32 + lo;
#pragma unroll
        for (int rr = 0; rr < 8; ++rr) {
          const int reg  = ((R & 1) << 3) + rr;
          const int lrow = (rr & 3) + ((rr >> 2) << 3) + (hi << 2);
          LBUF[lrow * GV + col] =
              ah_acc[t][reg] + al_acc[t][reg] * (1.0f / 2048.0f) + bfrag[t];
        }
      }
    }
    __syncthreads();
#pragma unroll
    for (int rr2 = 0; rr2 < 2; ++rr2) {
      const int lrow = wv * 2 + rr2;
      const int n = n0 + R * 16 + lrow;
#pragma unroll
      for (int g = 0; g < G_; ++g) {
        float L[5], GU[5];
#pragma unroll
        for (int j = 0; j < 5; ++j) {
          L[j]  = LBUF[lrow * GV + g * V_ + 64 * j + ln];
          GU[j] = gum[(size_t)n * GV + g * V_ + 64 * j + ln];
        }
        // local max/argmax (cols ascend with j -> first-occurrence tie-break)
        float m1 = L[0];         int a1 = ln;
        float m2 = L[0] + GU[0]; int a2 = ln;
#pragma unroll
        for (int j = 1; j < 5; ++j) {
          const int cix = 64 * j + ln;
          if (L[j] > m1) { m1 = L[j]; a1 = cix; }
          const float t2 = L[j] + GU[j];
          if (t2 > m2) { m2 = t2; a2 = cix; }
        }
        // wave reduce (prefer smaller index on exact ties)
        for (int off = 32; off; off >>= 1) {
          float om = __shfl_down(m1, off); int oa = __shfl_down(a1, off);
          if (om > m1 || (om == m1 && oa < a1)) { m1 = om; a1 = oa; }
          float om2 = __shfl_down(m2, off); int oa2 = __shfl_down(a2, off);
          if (om2 > m2 || (om2 == m2 && oa2 < a2)) { m2 = om2; a2 = oa2; }
        }
        m1 = __shfl(m1, 0); a1 = __shfl(a1, 0); a2 = __shfl(a2, 0);

        // softmax (no tau) for avg_probs
        float e[5], s = 0.f;
#pragma unroll
        for (int j = 0; j < 5; ++j) { e[j] = expf(L[j] - m1); s += e[j]; }
        for (int off = 32; off; off >>= 1) s += __shfl_down(s, off);
        s = __shfl(s, 0);
        const float inv = 1.0f / s;
#pragma unroll
        for (int j = 0; j < 5; ++j) racc[g][j] += e[j] * inv;

        if (ln == 0) {
          const int t = n & (T_ - 1);
          // packed 16-bit histogram bump (count <= 16, no carry possible)
          atomicAdd(&counts[(t * G_ + g) * (V_ / 2) + (a1 >> 1)],
                    1u << ((a1 & 1) * 16));
        }
        // quantized[n, g*D : (g+1)*D] = codebook[g, a2, :]
        const float2* cbr = (const float2*)(cb + (size_t)(g * V_ + a2) * D_);
        float2* op = (float2*)(out + (size_t)n * (G_ * D_) + g * D_);
        op[ln] = cbr[ln];
      }
    }
    __syncthreads();
  }

  // ---- block-level avg_probs partial: reduce 8 wave-private copies ----
  float* la = (float*)SB;  // [8][GV] = 20480 B
#pragma unroll
  for (int g = 0; g < G_; ++g)
#pragma unroll
    for (int j = 0; j < 5; ++j)
      la[wv * GV + g * V_ + 64 * j + ln] = racc[g][j];
  __syncthreads();
  for (int cix = tid; cix < GV; cix += THREADS) {
    float s = 0.f;
#pragma unroll
    for (int v = 0; v < 8; ++v) s += la[v * GV + cix];
    avg_part[(size_t)blk * GV + cix] = s;
  }
}

// Merged post-pass (one launch): blocks 0..511 = per-(t,g) histogram entropy;
// blocks 512..671 = column reduce of avg_part -> avgred.
__global__ __launch_bounds__(256) void k_post(
    const unsigned* __restrict__ counts, float* __restrict__ ent,
    const float* __restrict__ avg_part, float* __restrict__ avgred)
{
  const int b = blockIdx.x;
  const int lane = threadIdx.x & 63;
  if (b < (T_ * G_) / 4) {
    const int item = b * 4 + (threadIdx.x >> 6);  // 0..2047
    const unsigned* c = counts + (size_t)item * (V_ / 2);
    float s = 0.f;
#pragma unroll
    for (int j = 0; j < 3; ++j) {
      const int wi = lane + 64 * j;
      if (wi < V_ / 2) {
        const unsigned wd = c[wi];
        const float h0 = (float)(wd & 0xffffu) * (1.0f / B_);
        const float h1 = (float)(wd >> 16) * (1.0f / B_);
        s += h0 * logf(h0 + EPS_) + h1 * logf(h1 + EPS_);
      }
    }
    for (int off = 32; off; off >>= 1) s += __shfl_down(s, off);
    if (lane == 0) ent[item] = expf(-s);
  } else {
    const int cix = (b - (T_ * G_) / 4) * 4 + (threadIdx.x >> 6);  // 0..639
    float s = 0.f;
    for (int bb = lane; bb < NBLK; bb += 64) s += avg_part[(size_t)bb * GV + cix];
    for (int off = 32; off; off >>= 1) s += __shfl_down(s, off);
    if (lane == 0) avgred[cix] = s;
  }
}

// Finalize both scalars. Single block of 640 threads.
__global__ __launch_bounds__(GV) void k_final(
    const float* __restrict__ avgred, const float* __restrict__ ent,
    float* __restrict__ out2)
{
  __shared__ float sh[GV];   // p*log(p+eps) per column
  __shared__ float shc[GV];  // code-entropy partials
  const int tid = threadIdx.x;

  const float p = avgred[tid] * (1.0f / N_);
  sh[tid] = p * logf(p + EPS_);

  float cs = 0.f;
  for (int i = tid; i < T_ * G_; i += GV) cs += ent[i];
  shc[tid] = cs;
  __syncthreads();

  if (tid < 64) {
    float s0 = 0.f, s1 = 0.f, sc = 0.f;
    for (int j = tid; j < V_; j += 64) { s0 += sh[j]; s1 += sh[V_ + j]; }
    for (int j = tid; j < GV; j += 64) sc += shc[j];
    for (int off = 32; off; off >>= 1) {
      s0 += __shfl_down(s0, off);
      s1 += __shfl_down(s1, off);
      sc += __shfl_down(sc, off);
    }
    if (tid == 0) {
      out2[0] = sc;                          // code_perplexity
      out2[1] = expf(-s0) + expf(-s1);       // prob_perplexity
    }
  }
}

extern "C" void kernel_launch(void* const* d_in, const int* in_sizes, int n_in,
                              void* d_out, int out_size, void* d_ws, size_t ws_size,
                              hipStream_t stream) {
  const float* x   = (const float*)d_in[0];  // (B,T,F)
  const float* w   = (const float*)d_in[1];  // (G*V, F)
  const float* b   = (const float*)d_in[2];  // (G*V,)
  const float* cb  = (const float*)d_in[3];  // (1, G*V, D)
  const float* gum = (const float*)d_in[4];  // (B*T, G, V)
  float* out = (float*)d_out;                // quantized (N*G*D) ++ [code_ppl, prob_ppl]
  float* ws  = (float*)d_ws;

  unsigned* counts = (unsigned*)(ws + WS_COUNTS);
  float* avgp   = ws + WS_AVG;
  float* ent    = ws + WS_ENT;
  _Float16* wpk = (_Float16*)(ws + WS_WPK);
  float* avgred = ws + WS_AVGRED;

  hipMemsetAsync(counts, 0, (size_t)CNTW * sizeof(unsigned), stream);
  k_conv_w<<<64, 640, 0, stream>>>(w, wpk);
  k_fused<<<NBLK, THREADS, 0, stream>>>(x, wpk, b, cb, gum, out, counts, avgp);
  k_post<<<(T_ * G_) / 4 + GV / 4, 256, 0, stream>>>(counts, ent, avgp, avgred);
  k_final<<<1, GV, 0, stream>>>(avgred, ent, out + (size_t)N_ * G_ * D_);
}

// Round 6
// 187.461 us; speedup vs baseline: 1.8777x; 1.0059x over previous
//
#include <hip/hip_runtime.h>
#include <math.h>

// Problem constants (match reference)
#define B_   16
#define T_   1024
#define F_   512
#define G_   2
#define V_   320
#define D_   128
#define N_   (B_ * T_)      // 16384 tokens
#define GV   (G_ * V_)      // 640
#define EPS_ 1e-7f

// Swapped-operand fused GEMM: A = w fragments (L2-direct), B = x (in-reg),
// D[code][token] with token = lane. Dual scaled-limb f16 MFMA (R2-R4 numerics):
//   logits = xh*wh + 2^-11*(xl*wh + xh*wl),  limbs scaled by 2048 in f16.
#define ROWS    64           // tokens per block
#define THREADS 512          // 8 waves: tq(2) x g(2) x mh(2)
#define NBLK    (N_ / ROWS)  // 256 blocks
#define NC      32           // K=16 per chunk

typedef _Float16 half8 __attribute__((ext_vector_type(8)));
typedef _Float16 half4 __attribute__((ext_vector_type(4)));
typedef float f32x16 __attribute__((ext_vector_type(16)));

// Workspace layout (float slots). counts PACKED u32 (2 x u16, count<=16).
#define CNTW      (T_ * G_ * (V_ / 2))      // 327680 u32 words
#define WS_COUNTS 0
#define WS_AVG    CNTW                      // NBLK*GV = 163840
#define WS_ENT    (WS_AVG + NBLK * GV)      // T_*G_   = 2048
#define WS_WPK    (WS_ENT + T_ * G_)        // packed w limbs: 655360 halves
#define WS_AVGRED (WS_WPK + (GV * F_ * 2 / 2))

// ---- w -> packed fragment-order f16 limbs (+ fused counts zeroing) ----
// wpk half8 index: ((c*2 + limb)*20 + m)*64 + ln
//   contents: w[m*32 + (ln&31)][c*16 + (ln>>5)*8 + j] limb-converted.
__global__ __launch_bounds__(640) void k_conv_w(
    const float* __restrict__ w, _Float16* __restrict__ wpk,
    unsigned* __restrict__ counts)
{
  const int cl = blockIdx.x;     // 0..63 = c*2 + limb
  const int c = cl >> 1, limb = cl & 1;
#pragma unroll
  for (int z = 0; z < 8; ++z)    // zero counts: 64*640*8 = 327680 words
    counts[(size_t)z * 40960 + blockIdx.x * 640 + threadIdx.x] = 0u;
#pragma unroll
  for (int it = 0; it < 2; ++it) {
    const int t2 = threadIdx.x + it * 640;   // 0..1279
    const int m = t2 >> 6, ln = t2 & 63;
    const int row = m * 32 + (ln & 31);
    const int k0 = c * 16 + (ln >> 5) * 8;
    const float4 v0 = *(const float4*)(w + (size_t)row * F_ + k0);
    const float4 v1 = *(const float4*)(w + (size_t)row * F_ + k0 + 4);
    half8 h;
#pragma unroll
    for (int k = 0; k < 8; ++k) {
      const float vk = (k < 4) ? ((const float*)&v0)[k] : ((const float*)&v1)[k - 4];
      const _Float16 hk = (_Float16)vk;
      h[k] = limb ? (_Float16)((vk - (float)hk) * 2048.0f) : hk;
    }
    ((half8*)wpk)[((size_t)cl * 20 + m) * 64 + ln] = h;
  }
}

// Fused: barrier-free dual-limb MFMA GEMM + register softmax/argmax + gather.
__global__ __launch_bounds__(THREADS, 2) void k_fused(
    const float* __restrict__ x, const _Float16* __restrict__ wpk,
    const float* __restrict__ bias, const float* __restrict__ cb,
    const float* __restrict__ gum, float* __restrict__ out,
    unsigned* __restrict__ counts, float* __restrict__ avg_part)
{
  __shared__ float PLDS[32][644];     // 82.4 KB transpose buffer (phase 2 only)
  __shared__ float XCH[8][32][4];     // 4 KB cross-wave merge buffer
  const int tid = threadIdx.x;
  const int wv  = tid >> 6;
  const int ln  = tid & 63;
  const int lo  = ln & 31, hi = ln >> 5;
  const int tq  = wv & 1;             // token quarter (32 tokens each)
  const int g   = (wv >> 1) & 1;      // group
  const int mh  = wv >> 2;            // code half (160 codes each)
  const int blk = blockIdx.x;
  const int n0  = blk * ROWS;
  const int n   = n0 + tq * 32 + lo;  // this lane's token
  const int codebase = g * 320 + mh * 160;   // GLOBAL code index base

  // acc: D[code][token]; acc_h seeded with bias (code-row value, col-invariant)
  f32x16 ah[5], al[5];
#pragma unroll
  for (int t = 0; t < 5; ++t) {
#pragma unroll
    for (int q = 0; q < 4; ++q) {
      const float4 b4 = *(const float4*)(bias + codebase + t * 32 + q * 8 + 4 * hi);
#pragma unroll
      for (int rr = 0; rr < 4; ++rr) {
        ah[t][q * 4 + rr] = ((const float*)&b4)[rr];
        al[t][q * 4 + rr] = 0.0f;
      }
    }
  }

  const half8* wp8 = (const half8*)wpk;
  const float4* x4 = (const float4*)x;
  const size_t xbase = (size_t)n * (F_ / 4) + hi * 2;

  // ---- main loop: no LDS, no barriers; compiler pipelines via vmcnt ----
  for (int c = 0; c < NC; ++c) {
    const float4 v0 = x4[xbase + c * 4];
    const float4 v1 = x4[xbase + c * 4 + 1];
    half8 bh, bl;
#pragma unroll
    for (int k = 0; k < 8; ++k) {
      const float f = (k < 4) ? ((const float*)&v0)[k] : ((const float*)&v1)[k - 4];
      const _Float16 h = (_Float16)f;
      bh[k] = h;
      bl[k] = (_Float16)((f - (float)h) * 2048.0f);
    }
#pragma unroll
    for (int t = 0; t < 5; ++t) {
      const int m = g * 10 + mh * 5 + t;
      const half8 wh8 = wp8[((size_t)(c * 2 + 0) * 20 + m) * 64 + ln];
      const half8 wl8 = wp8[((size_t)(c * 2 + 1) * 20 + m) * 64 + ln];
      ah[t] = __builtin_amdgcn_mfma_f32_32x32x16_f16(wh8, bh, ah[t], 0, 0, 0);
      al[t] = __builtin_amdgcn_mfma_f32_32x32x16_f16(wl8, bh, al[t], 0, 0, 0);
      al[t] = __builtin_amdgcn_mfma_f32_32x32x16_f16(wh8, bl, al[t], 0, 0, 0);
    }
  }

  // ---- phase 2: per-lane logits for this token (80 code-slots) ----
  float Lv[5][16];
#pragma unroll
  for (int t = 0; t < 5; ++t)
#pragma unroll
    for (int i = 0; i < 16; ++i)
      Lv[t][i] = ah[t][i] + al[t][i] * (1.0f / 2048.0f);

  // local max/argmax; slot GLOBAL code = codebase + t*32 + q*8 + rr + 4*hi
  float m1 = -1e30f, m2 = -1e30f;
  int a1 = 0, a2 = 0;
#pragma unroll
  for (int t = 0; t < 5; ++t)
#pragma unroll
    for (int q = 0; q < 4; ++q) {
      const float4 gu = *(const float4*)(gum + (size_t)n * GV + codebase +
                                         t * 32 + q * 8 + 4 * hi);
#pragma unroll
      for (int rr = 0; rr < 4; ++rr) {
        const int cix = codebase + t * 32 + q * 8 + rr + 4 * hi;
        const float v = Lv[t][q * 4 + rr];
        if (v > m1 || (v == m1 && cix < a1)) { m1 = v; a1 = cix; }
        const float v2 = v + ((const float*)&gu)[rr];
        if (v2 > m2 || (v2 == m2 && cix < a2)) { m2 = v2; a2 = cix; }
      }
    }
  // merge across lane pair (hi halves interleave codes mod 8 -> compare codes)
  {
    const float om = __shfl_xor(m1, 32); const int oa = __shfl_xor(a1, 32);
    if (om > m1 || (om == m1 && oa < a1)) { m1 = om; a1 = oa; }
    const float om2 = __shfl_xor(m2, 32); const int oa2 = __shfl_xor(a2, 32);
    if (om2 > m2 || (om2 == m2 && oa2 < a2)) { m2 = om2; a2 = oa2; }
  }
  // merge across mh partner wave (wv ^ 4) via LDS
  if (hi == 0) {
    XCH[wv][lo][0] = m1;
    XCH[wv][lo][1] = m2;
    ((int*)&XCH[wv][lo][2])[0] = a1 | (a2 << 16);
  }
  __syncthreads();
  const int pw = wv ^ 4;
  {
    const float pm1 = XCH[pw][lo][0], pm2 = XCH[pw][lo][1];
    const int pa = ((const int*)&XCH[pw][lo][2])[0];
    const int pa1 = pa & 0xffff, pa2 = (int)((unsigned)pa >> 16);
    if (pm1 > m1 || (pm1 == m1 && pa1 < a1)) { m1 = pm1; a1 = pa1; }
    if (pm2 > m2 || (pm2 == m2 && pa2 < a2)) { m2 = pm2; a2 = pa2; }
  }
  // exp vs GLOBAL max (identical in both partner waves), local sum
  float e[5][16];
  float s = 0.0f;
#pragma unroll
  for (int t = 0; t < 5; ++t)
#pragma unroll
    for (int i = 0; i < 16; ++i) { e[t][i] = expf(Lv[t][i] - m1); s += e[t][i]; }
  s += __shfl_xor(s, 32);
  if (hi == 0) XCH[wv][lo][3] = s;
  __syncthreads();
  const float inv = 1.0f / (s + XCH[pw][lo][3]);

  // ---- avg_probs block partial: LDS transpose (token-major -> code sums) ----
  float rsum0 = 0.0f, rsum1 = 0.0f;
#pragma unroll
  for (int r = 0; r < 2; ++r) {
    if (r) __syncthreads();           // protect round-0 reads before overwrite
    if (tq == r) {
#pragma unroll
      for (int t = 0; t < 5; ++t)
#pragma unroll
        for (int q = 0; q < 4; ++q) {
          float4 p4;
#pragma unroll
          for (int rr = 0; rr < 4; ++rr)
            ((float*)&p4)[rr] = e[t][q * 4 + rr] * inv;
          *(float4*)&PLDS[lo][codebase + t * 32 + q * 8 + 4 * hi] = p4;
        }
    }
    __syncthreads();
    for (int i = 0; i < 32; ++i) {    // rotated reads: 2-way max (free)
      const int tr = (ln + i) & 31;
      rsum0 += PLDS[tr][tid];
      if (tid < 128) rsum1 += PLDS[tr][512 + tid];
    }
  }
  avg_part[(size_t)blk * GV + tid] = rsum0;
  if (tid < 128) avg_part[(size_t)blk * GV + 512 + tid] = rsum1;

  // ---- counts + codebook gather (mh==0 waves own the merged results) ----
  // R5-BUGFIX: a1/a2 are GLOBAL code indices [0,640).
  //   counts needs the WITHIN-GROUP index (R4 formula assumed [0,320)),
  //   cb row IS the global index (g*V + v == a2) -- do not add g*V_ again.
  if (mh == 0) {
    if (hi == 0) {
      const int t_ = n & (T_ - 1);
      const int va1 = a1 - g * V_;    // within-group code
      atomicAdd(&counts[(t_ * G_ + g) * (V_ / 2) + (va1 >> 1)],
                1u << ((va1 & 1) * 16));
    }
    const float2* cb2 = (const float2*)cb;
    float2* o2 = (float2*)out;
    for (int i = 0; i < 32; ++i) {
      const int aa = __shfl(a2, i);   // token (tq*32+i)'s gumbel argmax (global)
      const int nn = n0 + tq * 32 + i;
      o2[((size_t)nn * (G_ * D_) + g * D_) / 2 + ln] =
          cb2[(size_t)aa * (D_ / 2) + ln];
    }
  }
}

// Merged post-pass (one launch): blocks 0..511 = per-(t,g) histogram entropy;
// blocks 512..671 = column reduce of avg_part -> avgred.
__global__ __launch_bounds__(256) void k_post(
    const unsigned* __restrict__ counts, float* __restrict__ ent,
    const float* __restrict__ avg_part, float* __restrict__ avgred)
{
  const int b = blockIdx.x;
  const int lane = threadIdx.x & 63;
  if (b < (T_ * G_) / 4) {
    const int item = b * 4 + (threadIdx.x >> 6);  // 0..2047
    const unsigned* c = counts + (size_t)item * (V_ / 2);
    float s = 0.f;
#pragma unroll
    for (int j = 0; j < 3; ++j) {
      const int wi = lane + 64 * j;
      if (wi < V_ / 2) {
        const unsigned wd = c[wi];
        const float h0 = (float)(wd & 0xffffu) * (1.0f / B_);
        const float h1 = (float)(wd >> 16) * (1.0f / B_);
        s += h0 * logf(h0 + EPS_) + h1 * logf(h1 + EPS_);
      }
    }
    for (int off = 32; off; off >>= 1) s += __shfl_down(s, off);
    if (lane == 0) ent[item] = expf(-s);
  } else {
    const int cix = (b - (T_ * G_) / 4) * 4 + (threadIdx.x >> 6);  // 0..639
    float s = 0.f;
    for (int bb = lane; bb < NBLK; bb += 64) s += avg_part[(size_t)bb * GV + cix];
    for (int off = 32; off; off >>= 1) s += __shfl_down(s, off);
    if (lane == 0) avgred[cix] = s;
  }
}

// Finalize both scalars. Single block of 640 threads.
__global__ __launch_bounds__(GV) void k_final(
    const float* __restrict__ avgred, const float* __restrict__ ent,
    float* __restrict__ out2)
{
  __shared__ float sh[GV];   // p*log(p+eps) per column
  __shared__ float shc[GV];  // code-entropy partials
  const int tid = threadIdx.x;

  const float p = avgred[tid] * (1.0f / N_);
  sh[tid] = p * logf(p + EPS_);

  float cs = 0.f;
  for (int i = tid; i < T_ * G_; i += GV) cs += ent[i];
  shc[tid] = cs;
  __syncthreads();

  if (tid < 64) {
    float s0 = 0.f, s1 = 0.f, sc = 0.f;
    for (int j = tid; j < V_; j += 64) { s0 += sh[j]; s1 += sh[V_ + j]; }
    for (int j = tid; j < GV; j += 64) sc += shc[j];
    for (int off = 32; off; off >>= 1) {
      s0 += __shfl_down(s0, off);
      s1 += __shfl_down(s1, off);
      sc += __shfl_down(sc, off);
    }
    if (tid == 0) {
      out2[0] = sc;                          // code_perplexity
      out2[1] = expf(-s0) + expf(-s1);       // prob_perplexity
    }
  }
}

extern "C" void kernel_launch(void* const* d_in, const int* in_sizes, int n_in,
                              void* d_out, int out_size, void* d_ws, size_t ws_size,
                              hipStream_t stream) {
  const float* x   = (const float*)d_in[0];  // (B,T,F)
  const float* w   = (const float*)d_in[1];  // (G*V, F)
  const float* b   = (const float*)d_in[2];  // (G*V,)
  const float* cb  = (const float*)d_in[3];  // (1, G*V, D)
  const float* gum = (const float*)d_in[4];  // (B*T, G, V)
  float* out = (float*)d_out;                // quantized (N*G*D) ++ [code_ppl, prob_ppl]
  float* ws  = (float*)d_ws;

  unsigned* counts = (unsigned*)(ws + WS_COUNTS);
  float* avgp   = ws + WS_AVG;
  float* ent    = ws + WS_ENT;
  _Float16* wpk = (_Float16*)(ws + WS_WPK);
  float* avgred = ws + WS_AVGRED;

  k_conv_w<<<64, 640, 0, stream>>>(w, wpk, counts);
  k_fused<<<NBLK, THREADS, 0, stream>>>(x, wpk, b, cb, gum, out, counts, avgp);
  k_post<<<(T_ * G_) / 4 + GV / 4, 256, 0, stream>>>(counts, ent, avgp, avgred);
  k_final<<<1, GV, 0, stream>>>(avgred, ent, out + (size_t)N_ * G_ * D_);
}

// Round 7
// 181.064 us; speedup vs baseline: 1.9440x; 1.0353x over previous
//
#include <hip/hip_runtime.h>
#include <math.h>

// Problem constants (match reference)
#define B_   16
#define T_   1024
#define F_   512
#define G_   2
#define V_   320
#define D_   128
#define N_   (B_ * T_)      // 16384 tokens
#define GV   (G_ * V_)      // 640
#define EPS_ 1e-7f

// Fused-GEMM: single K-sweep, dual-limb f16 MFMA (R4 layout)
//   logits = xh*wh + 2^-11*(xl*wh + xh*wl)
// Schedule: 3-deep LDS pipeline, counted vmcnt (never 0 in steady state).
#define ROWS    64
#define THREADS 512          // 8 waves: 2(M) x 4(N) wave grid, wave tile 32x160
#define NBLK    (N_ / ROWS)  // 256 blocks -> 1 block/CU
#define NC      32           // K=16 per chunk

// LDS per buffer: B = 2 limbs x 20 frag-groups x 1KB = 40960 B (fragment-linear),
// A = 2 limbs x 2 mg x 1KB = 4096 B. Triple-buffered: 132 KB (1 block/CU; regs
// already cap occupancy at 2 waves/SIMD, so LDS is free budget).
#define BOFF  0
#define AOFF  40960
#define BUFSZ 45056
#define LDSZ  (3 * BUFSZ)

typedef _Float16 half8 __attribute__((ext_vector_type(8)));
typedef _Float16 half2_t __attribute__((ext_vector_type(2)));
typedef float f32x16 __attribute__((ext_vector_type(16)));

#define GLDS16(g, l)                                                           \
  __builtin_amdgcn_global_load_lds(                                            \
      (const __attribute__((address_space(1))) unsigned int*)(g),              \
      (__attribute__((address_space(3))) unsigned int*)(l), 16, 0, 0)

// Workspace layout (float slots). counts PACKED u32 (2 x u16, count<=16).
#define CNTW      (T_ * G_ * (V_ / 2))      // 327680 u32 words
#define WS_COUNTS 0
#define WS_AVG    CNTW                      // NBLK*GV = 163840
#define WS_ENT    (WS_AVG + NBLK * GV)      // T_*G_   = 2048
#define WS_WPK    (WS_ENT + T_ * G_)        // packed w limbs: 655360 halves
#define WS_AVGRED (WS_WPK + (GV * F_ * 2 / 2))

// ---- w -> packed fragment-order f16 limbs (+ fused counts zeroing) ----
// wpk half8 index: ((c*2 + limb)*20 + m)*64 + ln
//   contents: w[m*32 + (ln&31)][c*16 + (ln>>5)*8 + j] limb-converted.
__global__ __launch_bounds__(640) void k_conv_w(
    const float* __restrict__ w, _Float16* __restrict__ wpk,
    unsigned* __restrict__ counts)
{
  const int cl = blockIdx.x;     // 0..63 = c*2 + limb
  const int c = cl >> 1, limb = cl & 1;
#pragma unroll
  for (int z = 0; z < 8; ++z)    // zero counts: 64*640*8 = 327680 words
    counts[(size_t)z * 40960 + blockIdx.x * 640 + threadIdx.x] = 0u;
#pragma unroll
  for (int it = 0; it < 2; ++it) {
    const int t2 = threadIdx.x + it * 640;   // 0..1279
    const int m = t2 >> 6, ln = t2 & 63;
    const int row = m * 32 + (ln & 31);
    const int k0 = c * 16 + (ln >> 5) * 8;
    const float4 v0 = *(const float4*)(w + (size_t)row * F_ + k0);
    const float4 v1 = *(const float4*)(w + (size_t)row * F_ + k0 + 4);
    half8 h;
#pragma unroll
    for (int k = 0; k < 8; ++k) {
      const float vk = (k < 4) ? ((const float*)&v0)[k] : ((const float*)&v1)[k - 4];
      const _Float16 hk = (_Float16)vk;
      h[k] = limb ? (_Float16)((vk - (float)hk) * 2048.0f) : hk;
    }
    ((half8*)wpk)[((size_t)cl * 20 + m) * 64 + ln] = h;
  }
}

// Fused: 3-deep-pipelined dual-limb MFMA GEMM + softmax stats + gather.
__global__ __launch_bounds__(THREADS, 1) void k_fused(
    const float* __restrict__ x, const _Float16* __restrict__ wpk,
    const float* __restrict__ bias, const float* __restrict__ cb,
    const float* __restrict__ gum, float* __restrict__ out,
    unsigned* __restrict__ counts, float* __restrict__ avg_part)
{
  __shared__ __align__(16) unsigned char SB[LDSZ];
  const int tid = threadIdx.x;
  const int wv  = tid >> 6;           // 0..7
  const int ln  = tid & 63;
  const int lo  = ln & 31, hi = ln >> 5;
  const int wvm = wv >> 2, wvn = wv & 3;
  const int blk = blockIdx.x;
  const int n0  = blk * ROWS;

  f32x16 ah_acc[5], al_acc[5];
#pragma unroll
  for (int t = 0; t < 5; ++t)
#pragma unroll
    for (int i = 0; i < 16; ++i) { ah_acc[t][i] = 0.0f; al_acc[t][i] = 0.0f; }

  // A staging mapping: thread -> (row, k-pair); one float2 of x per chunk.
  const int arow = tid >> 3;          // 0..63
  const int akp  = tid & 7;           // k-pair within 16-k chunk
  const int awoff = (arow >> 5) * 1024 + (((akp >> 2) << 5) + (arow & 31)) * 16
                  + (akp & 3) * 4;    // within-limb offset; limb stride 2048
  const float2* x2 = (const float2*)x;
  const size_t xrowbase = (size_t)(n0 + arow) * (F_ / 2) + akp;

  // fragment read offsets RELATIVE to buffer base (lane-linear, conflict-free)
  const int aro_h = AOFF + 0 * 2048 + wvm * 1024 + ln * 16;
  const int aro_l = AOFF + 1 * 2048 + wvm * 1024 + ln * 16;
  int bro_h[5], bro_l[5];
#pragma unroll
  for (int t = 0; t < 5; ++t) {
    bro_h[t] = BOFF + (0 * 20 + wvn * 5 + t) * 1024 + ln * 16;
    bro_l[t] = BOFF + (1 * 20 + wvn * 5 + t) * 1024 + ln * 16;
  }

  auto STAGE_B = [&](int c, unsigned char* buf) {
#pragma unroll
    for (int i = 0; i < 5; ++i) {
      const int seg = wv * 5 + i;     // = limb*20 + m group (wave-uniform dest)
      GLDS16(wpk + ((size_t)(c * 40 + seg) * 64 + ln) * 8, buf + BOFF + seg * 1024);
    }
  };
  auto STAGE_A = [&](float2 xv, unsigned char* buf) {
    half2_t hh, hl;
#pragma unroll
    for (int k = 0; k < 2; ++k) {
      const float f = k ? xv.y : xv.x;
      const _Float16 h = (_Float16)f;
      hh[k] = h; hl[k] = (_Float16)((f - (float)h) * 2048.0f);
    }
    *(half2_t*)(buf + AOFF + awoff) = hh;
    *(half2_t*)(buf + AOFF + 2048 + awoff) = hl;
  };

  unsigned char* b0 = SB;             // chunk c
  unsigned char* b1 = SB + BUFSZ;     // chunk c+1
  unsigned char* b2 = SB + 2 * BUFSZ; // chunk c+2

  // ---- prologue: issue B(0),x(0),B(1),x(1); stage A(0); barrier vmcnt(6) ----
  STAGE_B(0, b0);
  const float2 xv0 = x2[xrowbase + 0 * 8];
  STAGE_B(1, b1);
  float2 xcur = x2[xrowbase + 1 * 8];
  STAGE_A(xv0, b0);                   // compiler waits x(0): vmcnt(6)
  __builtin_amdgcn_sched_barrier(0);
  asm volatile("s_waitcnt vmcnt(6) lgkmcnt(0)" ::: "memory");
  __builtin_amdgcn_s_barrier();
  __builtin_amdgcn_sched_barrier(0);

  // ---- main loop: one barrier per chunk, vmcnt(6) in steady state ----
  for (int cc = 0; cc < NC; ++cc) {
    float2 xnew = xcur;
    if (cc + 2 < NC) {                // issue prefetch for chunk cc+2
      STAGE_B(cc + 2, b2);
      xnew = x2[xrowbase + (cc + 2) * 8];
    }
    if (cc + 1 < NC) STAGE_A(xcur, b1);  // ds_write chunk cc+1's A
    // compute chunk cc from b0
    {
      const half8 ahf = *(const half8*)(b0 + aro_h);
      const half8 alf = *(const half8*)(b0 + aro_l);
#pragma unroll
      for (int t = 0; t < 5; ++t) {
        const half8 bh = *(const half8*)(b0 + bro_h[t]);
        const half8 bl = *(const half8*)(b0 + bro_l[t]);
        ah_acc[t] = __builtin_amdgcn_mfma_f32_32x32x16_f16(ahf, bh, ah_acc[t], 0, 0, 0);
        al_acc[t] = __builtin_amdgcn_mfma_f32_32x32x16_f16(alf, bh, al_acc[t], 0, 0, 0);
        al_acc[t] = __builtin_amdgcn_mfma_f32_32x32x16_f16(ahf, bl, al_acc[t], 0, 0, 0);
      }
    }
    // rotate buffers; barrier with counted vmcnt (c+2's 6 ops stay in flight)
    unsigned char* tmp = b0; b0 = b1; b1 = b2; b2 = tmp;
    xcur = xnew;
    __builtin_amdgcn_sched_barrier(0);
    if (cc + 2 < NC)
      asm volatile("s_waitcnt vmcnt(6) lgkmcnt(0)" ::: "memory");
    else
      asm volatile("s_waitcnt vmcnt(0) lgkmcnt(0)" ::: "memory");
    __builtin_amdgcn_s_barrier();
    __builtin_amdgcn_sched_barrier(0);
  }

  // ---- phase 2 (verbatim R4): softmax / argmax / gather via 16-row slabs ----
  float bfrag[5];
#pragma unroll
  for (int t = 0; t < 5; ++t) bfrag[t] = bias[wvn * 160 + t * 32 + lo];

  float racc[G_][5];
#pragma unroll
  for (int g = 0; g < G_; ++g)
#pragma unroll
    for (int j = 0; j < 5; ++j) racc[g][j] = 0.f;

  float* LBUF = (float*)SB;  // [16][640] = 40 KB

#pragma unroll
  for (int R = 0; R < 4; ++R) {
    // writers: waves with wvm==R>>1 dump regs 8*(R&1)..+7 (C/D layout:
    // col=lane&31, row=(reg&3)+8*(reg>>2)+4*hi) -> rows 16R..16R+15
    if (wvm == (R >> 1)) {
#pragma unroll
      for (int t = 0; t < 5; ++t) {
        const int col = wvn * 160 + t * 32 + lo;
#pragma unroll
        for (int rr = 0; rr < 8; ++rr) {
          const int reg  = ((R & 1) << 3) + rr;
          const int lrow = (rr & 3) + ((rr >> 2) << 3) + (hi << 2);
          LBUF[lrow * GV + col] =
              ah_acc[t][reg] + al_acc[t][reg] * (1.0f / 2048.0f) + bfrag[t];
        }
      }
    }
    __syncthreads();
#pragma unroll
    for (int rr2 = 0; rr2 < 2; ++rr2) {
      const int lrow = wv * 2 + rr2;
      const int n = n0 + R * 16 + lrow;
#pragma unroll
      for (int g = 0; g < G_; ++g) {
        float L[5], GU[5];
#pragma unroll
        for (int j = 0; j < 5; ++j) {
          L[j]  = LBUF[lrow * GV + g * V_ + 64 * j + ln];
          GU[j] = gum[(size_t)n * GV + g * V_ + 64 * j + ln];
        }
        // local max/argmax (cols ascend with j -> first-occurrence tie-break)
        float m1 = L[0];         int a1 = ln;
        float m2 = L[0] + GU[0]; int a2 = ln;
#pragma unroll
        for (int j = 1; j < 5; ++j) {
          const int cix = 64 * j + ln;
          if (L[j] > m1) { m1 = L[j]; a1 = cix; }
          const float t2 = L[j] + GU[j];
          if (t2 > m2) { m2 = t2; a2 = cix; }
        }
        // wave reduce (prefer smaller index on exact ties)
        for (int off = 32; off; off >>= 1) {
          float om = __shfl_down(m1, off); int oa = __shfl_down(a1, off);
          if (om > m1 || (om == m1 && oa < a1)) { m1 = om; a1 = oa; }
          float om2 = __shfl_down(m2, off); int oa2 = __shfl_down(a2, off);
          if (om2 > m2 || (om2 == m2 && oa2 < a2)) { m2 = om2; a2 = oa2; }
        }
        m1 = __shfl(m1, 0); a1 = __shfl(a1, 0); a2 = __shfl(a2, 0);

        // softmax (no tau) for avg_probs
        float e[5], s = 0.f;
#pragma unroll
        for (int j = 0; j < 5; ++j) { e[j] = expf(L[j] - m1); s += e[j]; }
        for (int off = 32; off; off >>= 1) s += __shfl_down(s, off);
        s = __shfl(s, 0);
        const float inv = 1.0f / s;
#pragma unroll
        for (int j = 0; j < 5; ++j) racc[g][j] += e[j] * inv;

        if (ln == 0) {
          const int t = n & (T_ - 1);
          // packed 16-bit histogram bump (count <= 16, no carry possible)
          atomicAdd(&counts[(t * G_ + g) * (V_ / 2) + (a1 >> 1)],
                    1u << ((a1 & 1) * 16));
        }
        // quantized[n, g*D : (g+1)*D] = codebook[g, a2, :]
        const float2* cbr = (const float2*)(cb + (size_t)(g * V_ + a2) * D_);
        float2* op = (float2*)(out + (size_t)n * (G_ * D_) + g * D_);
        op[ln] = cbr[ln];
      }
    }
    __syncthreads();
  }

  // ---- block-level avg_probs partial: reduce 8 wave-private copies ----
  float* la = (float*)SB;  // [8][GV] = 20480 B
#pragma unroll
  for (int g = 0; g < G_; ++g)
#pragma unroll
    for (int j = 0; j < 5; ++j)
      la[wv * GV + g * V_ + 64 * j + ln] = racc[g][j];
  __syncthreads();
  for (int cix = tid; cix < GV; cix += THREADS) {
    float s = 0.f;
#pragma unroll
    for (int v = 0; v < 8; ++v) s += la[v * GV + cix];
    avg_part[(size_t)blk * GV + cix] = s;
  }
}

// Merged post-pass (one launch): blocks 0..511 = per-(t,g) histogram entropy;
// blocks 512..671 = column reduce of avg_part -> avgred.
__global__ __launch_bounds__(256) void k_post(
    const unsigned* __restrict__ counts, float* __restrict__ ent,
    const float* __restrict__ avg_part, float* __restrict__ avgred)
{
  const int b = blockIdx.x;
  const int lane = threadIdx.x & 63;
  if (b < (T_ * G_) / 4) {
    const int item = b * 4 + (threadIdx.x >> 6);  // 0..2047
    const unsigned* c = counts + (size_t)item * (V_ / 2);
    float s = 0.f;
#pragma unroll
    for (int j = 0; j < 3; ++j) {
      const int wi = lane + 64 * j;
      if (wi < V_ / 2) {
        const unsigned wd = c[wi];
        const float h0 = (float)(wd & 0xffffu) * (1.0f / B_);
        const float h1 = (float)(wd >> 16) * (1.0f / B_);
        s += h0 * logf(h0 + EPS_) + h1 * logf(h1 + EPS_);
      }
    }
    for (int off = 32; off; off >>= 1) s += __shfl_down(s, off);
    if (lane == 0) ent[item] = expf(-s);
  } else {
    const int cix = (b - (T_ * G_) / 4) * 4 + (threadIdx.x >> 6);  // 0..639
    float s = 0.f;
    for (int bb = lane; bb < NBLK; bb += 64) s += avg_part[(size_t)bb * GV + cix];
    for (int off = 32; off; off >>= 1) s += __shfl_down(s, off);
    if (lane == 0) avgred[cix] = s;
  }
}

// Finalize both scalars. Single block of 640 threads.
__global__ __launch_bounds__(GV) void k_final(
    const float* __restrict__ avgred, const float* __restrict__ ent,
    float* __restrict__ out2)
{
  __shared__ float sh[GV];   // p*log(p+eps) per column
  __shared__ float shc[GV];  // code-entropy partials
  const int tid = threadIdx.x;

  const float p = avgred[tid] * (1.0f / N_);
  sh[tid] = p * logf(p + EPS_);

  float cs = 0.f;
  for (int i = tid; i < T_ * G_; i += GV) cs += ent[i];
  shc[tid] = cs;
  __syncthreads();

  if (tid < 64) {
    float s0 = 0.f, s1 = 0.f, sc = 0.f;
    for (int j = tid; j < V_; j += 64) { s0 += sh[j]; s1 += sh[V_ + j]; }
    for (int j = tid; j < GV; j += 64) sc += shc[j];
    for (int off = 32; off; off >>= 1) {
      s0 += __shfl_down(s0, off);
      s1 += __shfl_down(s1, off);
      sc += __shfl_down(sc, off);
    }
    if (tid == 0) {
      out2[0] = sc;                          // code_perplexity
      out2[1] = expf(-s0) + expf(-s1);       // prob_perplexity
    }
  }
}

extern "C" void kernel_launch(void* const* d_in, const int* in_sizes, int n_in,
                              void* d_out, int out_size, void* d_ws, size_t ws_size,
                              hipStream_t stream) {
  const float* x   = (const float*)d_in[0];  // (B,T,F)
  const float* w   = (const float*)d_in[1];  // (G*V, F)
  const float* b   = (const float*)d_in[2];  // (G*V,)
  const float* cb  = (const float*)d_in[3];  // (1, G*V, D)
  const float* gum = (const float*)d_in[4];  // (B*T, G, V)
  float* out = (float*)d_out;                // quantized (N*G*D) ++ [code_ppl, prob_ppl]
  float* ws  = (float*)d_ws;

  unsigned* counts = (unsigned*)(ws + WS_COUNTS);
  float* avgp   = ws + WS_AVG;
  float* ent    = ws + WS_ENT;
  _Float16* wpk = (_Float16*)(ws + WS_WPK);
  float* avgred = ws + WS_AVGRED;

  k_conv_w<<<64, 640, 0, stream>>>(w, wpk, counts);
  k_fused<<<NBLK, THREADS, 0, stream>>>(x, wpk, b, cb, gum, out, counts, avgp);
  k_post<<<(T_ * G_) / 4 + GV / 4, 256, 0, stream>>>(counts, ent, avgp, avgred);
  k_final<<<1, GV, 0, stream>>>(avgred, ent, out + (size_t)N_ * G_ * D_);
}